// Round 14
// baseline (148.953 us; speedup 1.0000x reference)
//
#include <hip/hip_runtime.h>

#define NB   4
#define NSEQ 4096
#define DK   64
#define NTOK (NB * NSEQ)

#define QK_SCALE 1.2011224087864498f   // sqrt(log2(e))

typedef __attribute__((ext_vector_type(8))) _Float16 half8;
typedef __attribute__((ext_vector_type(2))) _Float16 half2v;
typedef __attribute__((ext_vector_type(2))) __fp16 fp16x2;
typedef __attribute__((ext_vector_type(4))) float f32x4;

__device__ __forceinline__ float fast_exp2(float x) {
#if __has_builtin(__builtin_amdgcn_exp2f)
    return __builtin_amdgcn_exp2f(x);
#else
    return exp2f(x);
#endif
}

__device__ __forceinline__ half2v pack_f16(float a, float b) {
#if __has_builtin(__builtin_amdgcn_cvt_pkrtz)
    union { fp16x2 f; half2v h; } c;
    c.f = __builtin_amdgcn_cvt_pkrtz(a, b);
    return c.h;
#else
    half2v r; r[0] = (_Float16)a; r[1] = (_Float16)b; return r;
#endif
}

__device__ __forceinline__ half8 u4_to_h8(uint4 u) {
    union { uint4 u; half8 h; } c; c.u = u; return c.h;
}

#define AS3U(p) ((__attribute__((address_space(3))) unsigned int*)(p))
#define AS1U(p) ((const __attribute__((address_space(1))) unsigned int*)(p))

// ---------------------------------------------------------------------------
// Vt global layout FRAGMENT-MAJOR (f16): Vt_frag[b][jc][ct][lane] x 8 f16,
// lane = q*16 + rit holds V[d = ct*16 + rit][j = jc*32 + q*8 .. +8].
// ---------------------------------------------------------------------------

// ---------------------------------------------------------------------------
// Kernel A: Qs/Ks = (x.wq/wk)*QK_SCALE, Vt_frag = f16(x@Wv^T+bv)
// ---------------------------------------------------------------------------
__global__ __launch_bounds__(512) void qkv_kernel(
    const float* __restrict__ x, const float* __restrict__ Wv,
    const float* __restrict__ bv, const float* __restrict__ wq,
    const float* __restrict__ wk,
    float* __restrict__ Qs, float* __restrict__ Ks, unsigned short* __restrict__ Vt)
{
    __shared__ float x_lds[64 * 68];
    __shared__ float wvt[64 * 68];        // wvt[d*68+e] = Wv[e*64+d]
    __shared__ float wqk[128];
    __shared__ float bvl[64];
    __shared__ unsigned short vt_lds[64 * 72];   // [e][tok], f16 bits

    const int t = threadIdx.x;
    const int tok0 = blockIdx.x * 64;

    #pragma unroll
    for (int r = 0; r < 2; ++r) {
        int f = t + 512 * r;
        int row = f >> 4, c4 = f & 15;
        float4 v = ((const float4*)(x + (size_t)(tok0 + row) * DK))[c4];
        *(float4*)&x_lds[row * 68 + c4 * 4] = v;
    }
    #pragma unroll
    for (int r = 0; r < 2; ++r) {
        int f = t + 512 * r;
        int e = f >> 4, c4 = f & 15;
        float4 v = ((const float4*)(Wv + e * DK))[c4];
        wvt[(c4 * 4 + 0) * 68 + e] = v.x;
        wvt[(c4 * 4 + 1) * 68 + e] = v.y;
        wvt[(c4 * 4 + 2) * 68 + e] = v.z;
        wvt[(c4 * 4 + 3) * 68 + e] = v.w;
    }
    if (t < 64) { wqk[t * 2] = wq[t]; wqk[t * 2 + 1] = wk[t]; bvl[t] = bv[t]; }
    __syncthreads();

    const int tok = t >> 3, oc = t & 7;
    const int e0 = oc * 8;
    float acc[8];
    #pragma unroll
    for (int ee = 0; ee < 8; ++ee) acc[ee] = bvl[e0 + ee];

    for (int d = 0; d < DK; d += 4) {
        float4 x4 = *(const float4*)&x_lds[tok * 68 + d];
        const float xs[4] = {x4.x, x4.y, x4.z, x4.w};
        #pragma unroll
        for (int dd = 0; dd < 4; ++dd) {
            float xv = xs[dd];
            const float4* wrow = (const float4*)&wvt[(d + dd) * 68 + e0];
            float4 wa = wrow[0], wb = wrow[1];
            acc[0] += xv * wa.x; acc[1] += xv * wa.y;
            acc[2] += xv * wa.z; acc[3] += xv * wa.w;
            acc[4] += xv * wb.x; acc[5] += xv * wb.y;
            acc[6] += xv * wb.z; acc[7] += xv * wb.w;
        }
    }
    #pragma unroll
    for (int k = 0; k < 8; ++k) {
        _Float16 hv = (_Float16)acc[k];
        vt_lds[(e0 + k) * 72 + tok] = *(unsigned short*)&hv;
    }

    if (t < 128) {
        const int tk = t & 63;
        const int sel = (t >= 64);
        float a = 0.f;
        for (int d = 0; d < DK; ++d)
            a += x_lds[tk * 68 + d] * wqk[d * 2 + sel];
        (sel ? Ks : Qs)[tok0 + tk] = a * QK_SCALE;
    }
    __syncthreads();

    // fragment-major store
    const int bb = tok0 >> 12, n0 = tok0 & 4095;
    {
        const int c = t >> 6, d = t & 63;
        uint4 v = *(const uint4*)((const char*)vt_lds + d * 144 + c * 16);
        const int jc   = (n0 >> 5) + (c >> 2);
        const int lane = (c & 3) * 16 + (d & 15);
        const int ct   = d >> 4;
        unsigned short* dst = Vt + ((((size_t)bb * 128 + jc) * 4 + ct) * 64 + lane) * 8;
        *(uint4*)dst = v;
    }
}

// ---------------------------------------------------------------------------
// Kernel B: MFMA attention + residual + layernorm. (identical to round 13)
// MEASUREMENT ROUND: nrep=4 so attn tops the profile with full counters.
// ---------------------------------------------------------------------------
extern __shared__ float smem[];

__global__ __launch_bounds__(1024, 4) void attn_kernel(
    const float* __restrict__ x,
    const float* __restrict__ Qsg, const float* __restrict__ Ksg,
    const unsigned short* __restrict__ Vt,
    const float* __restrict__ gamma, const float* __restrict__ beta,
    float* __restrict__ out, int nrep)
{
    float* k_lds = smem;                          // 4096 floats
    unsigned short* vs = (unsigned short*)(smem + 4096);   // 2 x 32768 f16 (128 KB)
    float* red   = smem + 4096;                   // 8 slots x 64 x 68 (post-loop reuse)
    float* dred  = smem + 4096 + 8 * 64 * 68;     // 8 x 64

    const int t    = threadIdx.x;
    const int B    = blockIdx.x;
    const int b    = (B & 7) >> 1;                         // batch <- XCD pair
    const int i0   = (((B >> 3) << 1) | (B & 1)) << 6;     // i-tile
    const int w    = t >> 6;
    const int lane = t & 63;
    const int rit  = lane & 15;
    const int q    = lane >> 4;
    const int rgrp = w >> 3;          // 0..1: 32-row group
    const int js   = w & 7;           // 0..7: 64-j piece within each round

    ((float4*)k_lds)[t] = ((const float4*)(Ksg + (size_t)b * 4096))[t];

    const float Qs0 = Qsg[b * 4096 + i0 + rgrp * 32 + rit];
    const float Qs1 = Qsg[b * 4096 + i0 + rgrp * 32 + 16 + rit];

    const _Float16 onef = (_Float16)1.0f;
    const half8 vones = {onef, onef, onef, onef, onef, onef, onef, onef};
    const half2v c2 = {(_Float16)3.2552083e-4f, (_Float16)3.2552083e-4f};
    const half2v c1 = {(_Float16)7.8125e-3f, (_Float16)7.8125e-3f};
    const half2v c0 = {(_Float16)0.125f, (_Float16)0.125f};
    const half2v h1 = {onef, onef};

    const unsigned short* Vtb0 = Vt + (size_t)b * 262144;

    for (int rep = 0; rep < nrep; ++rep) {

    f32x4 acc[2][4] = {};
    f32x4 accd[2] = {};

    // ---- prologue: stage round 0 into buf 0 (4 contiguous 1 KB DMA rows/wave)
    #pragma unroll
    for (int i = 0; i < 4; ++i) {
        const int row = w + 16 * i;
        const unsigned short* g = Vtb0 + row * 512 + lane * 8;
        unsigned short* l = vs + row * 512;
#if __has_builtin(__builtin_amdgcn_global_load_lds)
        __builtin_amdgcn_global_load_lds(AS1U(g), AS3U(l), 16, 0, 0);
#else
        *(uint4*)(l + lane * 8) = *(const uint4*)g;
#endif
    }
    __syncthreads();   // k_lds + buf0 ready

    for (int r = 0; r < 8; ++r) {
        const int bf = r & 1;
        if (r < 7) {
            #pragma unroll
            for (int i = 0; i < 4; ++i) {
                const int row = w + 16 * i;
                const unsigned short* g = Vtb0 + (r + 1) * 32768 + row * 512 + lane * 8;
                unsigned short* l = vs + (bf ^ 1) * 32768 + row * 512;
#if __has_builtin(__builtin_amdgcn_global_load_lds)
                __builtin_amdgcn_global_load_lds(AS1U(g), AS3U(l), 16, 0, 0);
#else
                *(uint4*)(l + lane * 8) = *(const uint4*)g;
#endif
            }
        }

        // ---- compute: 2 MFMA k-steps from buf bf (conflict-free b128 reads)
        #pragma unroll
        for (int sl = 0; sl < 2; ++sl) {
            const int jcl = js * 2 + sl;
            const unsigned short* vf = vs + bf * 32768 + jcl * 2048 + lane * 8;
            uint4 bu0 = *(const uint4*)(vf);
            uint4 bu1 = *(const uint4*)(vf + 512);
            uint4 bu2 = *(const uint4*)(vf + 1024);
            uint4 bu3 = *(const uint4*)(vf + 1536);

            const float* kn = k_lds + r * 512 + jcl * 32 + q * 8;   // broadcast
            float4 ka = *(const float4*)(kn);
            float4 kb = *(const float4*)(kn + 4);
            float kv[8] = {ka.x, ka.y, ka.z, ka.w, kb.x, kb.y, kb.z, kb.w};

            // ---- scores: f32 exp2 -> packed f16 poly (A-frag built packed)
            half2v w0p[4], w1p[4];
            #pragma unroll
            for (int jp = 0; jp < 4; ++jp) {
                float d0a = Qs0 - kv[2 * jp],     d0b = Qs0 - kv[2 * jp + 1];
                float g0a = fast_exp2(-d0a * d0a), g0b = fast_exp2(-d0b * d0b);
                half2v g0 = pack_f16(g0a, g0b);
                w0p[jp] = g0 * (g0 * (g0 * c2 + c1) + c0) + h1;  // exp(g/8)

                float d1a = Qs1 - kv[2 * jp],     d1b = Qs1 - kv[2 * jp + 1];
                float g1a = fast_exp2(-d1a * d1a), g1b = fast_exp2(-d1b * d1b);
                half2v g1 = pack_f16(g1a, g1b);
                w1p[jp] = g1 * (g1 * (g1 * c2 + c1) + c0) + h1;
            }
            union { half2v p[4]; half8 h; } ua0, ua1;
            #pragma unroll
            for (int jp = 0; jp < 4; ++jp) { ua0.p[jp] = w0p[jp]; ua1.p[jp] = w1p[jp]; }
            half8 a0 = ua0.h, a1 = ua1.h;

            half8 b0 = u4_to_h8(bu0), b1 = u4_to_h8(bu1);
            half8 b2 = u4_to_h8(bu2), b3 = u4_to_h8(bu3);
            acc[0][0] = __builtin_amdgcn_mfma_f32_16x16x32_f16(a0, b0, acc[0][0], 0, 0, 0);
            acc[0][1] = __builtin_amdgcn_mfma_f32_16x16x32_f16(a0, b1, acc[0][1], 0, 0, 0);
            acc[0][2] = __builtin_amdgcn_mfma_f32_16x16x32_f16(a0, b2, acc[0][2], 0, 0, 0);
            acc[0][3] = __builtin_amdgcn_mfma_f32_16x16x32_f16(a0, b3, acc[0][3], 0, 0, 0);
            acc[1][0] = __builtin_amdgcn_mfma_f32_16x16x32_f16(a1, b0, acc[1][0], 0, 0, 0);
            acc[1][1] = __builtin_amdgcn_mfma_f32_16x16x32_f16(a1, b1, acc[1][1], 0, 0, 0);
            acc[1][2] = __builtin_amdgcn_mfma_f32_16x16x32_f16(a1, b2, acc[1][2], 0, 0, 0);
            acc[1][3] = __builtin_amdgcn_mfma_f32_16x16x32_f16(a1, b3, acc[1][3], 0, 0, 0);
            accd[0]   = __builtin_amdgcn_mfma_f32_16x16x32_f16(a0, vones, accd[0], 0, 0, 0);
            accd[1]   = __builtin_amdgcn_mfma_f32_16x16x32_f16(a1, vones, accd[1], 0, 0, 0);
        }
        __syncthreads();   // publishes next buf (DMA drained), protects buf reuse
    }

    // ---- write partials into red (reuses staging region; all reads done)
    {
        float* rbase = red + (size_t)js * (64 * 68);
        #pragma unroll
        for (int rt = 0; rt < 2; ++rt)
            #pragma unroll
            for (int ct = 0; ct < 4; ++ct)
                #pragma unroll
                for (int rg = 0; rg < 4; ++rg)
                    rbase[(rgrp * 32 + rt * 16 + q * 4 + rg) * 68 + ct * 16 + rit]
                        = acc[rt][ct][rg];
        if (rit == 0) {
            #pragma unroll
            for (int rt = 0; rt < 2; ++rt)
                #pragma unroll
                for (int rg = 0; rg < 4; ++rg)
                    dred[js * 64 + rgrp * 32 + rt * 16 + q * 4 + rg] = accd[rt][rg];
        }
    }
    __syncthreads();

    // ---- coalesced epilogue: thread = (row, 4 consecutive cols)
    {
        const int row = t >> 4, cg = t & 15, c0i = cg * 4;
        float dsum = 0.f;
        #pragma unroll
        for (int sl = 0; sl < 8; ++sl) dsum += dred[sl * 64 + row];
        const float inv = 1.0f / dsum;
        const size_t rowg = (size_t)(b * 4096 + i0 + row);

        float4 num = make_float4(0.f, 0.f, 0.f, 0.f);
        #pragma unroll
        for (int sl = 0; sl < 8; ++sl) {
            float4 r4 = *(const float4*)&red[(size_t)sl * (64 * 68) + row * 68 + c0i];
            num.x += r4.x; num.y += r4.y; num.z += r4.z; num.w += r4.w;
        }
        const float4 x4 = *(const float4*)(x + rowg * 64 + c0i);
        float4 h;
        h.x = num.x * inv + x4.x;
        h.y = num.y * inv + x4.y;
        h.z = num.z * inv + x4.z;
        h.w = num.w * inv + x4.w;

        float sm = h.x + h.y + h.z + h.w;
        float ss = h.x * h.x + h.y * h.y + h.z * h.z + h.w * h.w;
        #pragma unroll
        for (int m = 1; m < 16; m <<= 1) { sm += __shfl_xor(sm, m); ss += __shfl_xor(ss, m); }
        const float mu   = sm * 0.015625f;
        const float var  = ss * 0.015625f - mu * mu;
        const float rstd = rsqrtf(var + 1e-5f);

        const float4 g4 = *(const float4*)(gamma + c0i);
        const float4 b4 = *(const float4*)(beta + c0i);
        float4 o;
        o.x = (h.x - mu) * rstd * g4.x + b4.x;
        o.y = (h.y - mu) * rstd * g4.y + b4.y;
        o.z = (h.z - mu) * rstd * g4.z + b4.z;
        o.w = (h.w - mu) * rstd * g4.w + b4.w;
        *(float4*)(out + rowg * 64 + c0i) = o;
    }
    __syncthreads();   // rep isolation
    }
}

// ---------------------------------------------------------------------------
extern "C" void kernel_launch(void* const* d_in, const int* in_sizes, int n_in,
                              void* d_out, int out_size, void* d_ws, size_t ws_size,
                              hipStream_t stream)
{
    const float* x     = (const float*)d_in[0];
    const float* Wv    = (const float*)d_in[1];
    const float* bv    = (const float*)d_in[2];
    const float* wq    = (const float*)d_in[3];
    const float* wk    = (const float*)d_in[4];
    const float* gamma = (const float*)d_in[5];
    const float* beta  = (const float*)d_in[6];
    float* out = (float*)d_out;

    float* Qs = (float*)d_ws;
    float* Ks = Qs + NTOK;
    unsigned short* Vt = (unsigned short*)(Ks + NTOK);

    // dynamic LDS: k 16384 + union(red 139264 / Vstage 131072) + dred 2048 = 157696 B
    const int attn_lds = 4096 * 4 + 8 * 64 * 68 * 4 + 8 * 64 * 4;
    (void)hipFuncSetAttribute((const void*)attn_kernel,
                              hipFuncAttributeMaxDynamicSharedMemorySize, attn_lds);

    qkv_kernel<<<dim3(NTOK / 64), dim3(512), 0, stream>>>(x, Wv, bv, wq, wk, Qs, Ks, Vt);
    // MEASUREMENT: nrep=4 (idempotent reps, graph-safe) -> attn tops the profile
    attn_kernel<<<dim3(NB * (NSEQ / 64)), dim3(1024), attn_lds, stream>>>(
        x, Qs, Ks, Vt, gamma, beta, out, 4);
}

// Round 15
// 91.335 us; speedup vs baseline: 1.6308x; 1.6308x over previous
//
#include <hip/hip_runtime.h>

#define NB   4
#define NSEQ 4096
#define DK   64
#define NTOK (NB * NSEQ)

#define QK_SCALE 1.2011224087864498f   // sqrt(log2(e))

typedef __attribute__((ext_vector_type(8))) _Float16 half8;
typedef __attribute__((ext_vector_type(2))) _Float16 half2v;
typedef __attribute__((ext_vector_type(2))) __fp16 fp16x2;
typedef __attribute__((ext_vector_type(4))) float f32x4;

__device__ __forceinline__ float fast_exp2(float x) {
#if __has_builtin(__builtin_amdgcn_exp2f)
    return __builtin_amdgcn_exp2f(x);
#else
    return exp2f(x);
#endif
}

__device__ __forceinline__ half2v pack_f16(float a, float b) {
#if __has_builtin(__builtin_amdgcn_cvt_pkrtz)
    union { fp16x2 f; half2v h; } c;
    c.f = __builtin_amdgcn_cvt_pkrtz(a, b);
    return c.h;
#else
    half2v r; r[0] = (_Float16)a; r[1] = (_Float16)b; return r;
#endif
}

__device__ __forceinline__ half8 u4_to_h8(uint4 u) {
    union { uint4 u; half8 h; } c; c.u = u; return c.h;
}

// ---------------------------------------------------------------------------
// Vt global layout FRAGMENT-MAJOR (f16): Vt_frag[b][jc][ct][lane] x 8 f16,
// lane = q*16 + rit holds V[d = ct*16 + rit][j = jc*32 + q*8 .. +8].
// One (jc,ct) block = 64 lanes x 16 B = 1 KB contiguous -> a direct global
// B-fragment load is a single fully-coalesced 1 KB wave transaction.
// ---------------------------------------------------------------------------

// ---------------------------------------------------------------------------
// Kernel A: Qs/Ks = (x.wq/wk)*QK_SCALE, Vt_frag = f16(x@Wv^T+bv)
// ---------------------------------------------------------------------------
__global__ __launch_bounds__(512) void qkv_kernel(
    const float* __restrict__ x, const float* __restrict__ Wv,
    const float* __restrict__ bv, const float* __restrict__ wq,
    const float* __restrict__ wk,
    float* __restrict__ Qs, float* __restrict__ Ks, unsigned short* __restrict__ Vt)
{
    __shared__ float x_lds[64 * 68];
    __shared__ float wvt[64 * 68];        // wvt[d*68+e] = Wv[e*64+d]
    __shared__ float wqk[128];
    __shared__ float bvl[64];
    __shared__ unsigned short vt_lds[64 * 72];   // [e][tok], f16 bits

    const int t = threadIdx.x;
    const int tok0 = blockIdx.x * 64;

    #pragma unroll
    for (int r = 0; r < 2; ++r) {
        int f = t + 512 * r;
        int row = f >> 4, c4 = f & 15;
        float4 v = ((const float4*)(x + (size_t)(tok0 + row) * DK))[c4];
        *(float4*)&x_lds[row * 68 + c4 * 4] = v;
    }
    #pragma unroll
    for (int r = 0; r < 2; ++r) {
        int f = t + 512 * r;
        int e = f >> 4, c4 = f & 15;
        float4 v = ((const float4*)(Wv + e * DK))[c4];
        wvt[(c4 * 4 + 0) * 68 + e] = v.x;
        wvt[(c4 * 4 + 1) * 68 + e] = v.y;
        wvt[(c4 * 4 + 2) * 68 + e] = v.z;
        wvt[(c4 * 4 + 3) * 68 + e] = v.w;
    }
    if (t < 64) { wqk[t * 2] = wq[t]; wqk[t * 2 + 1] = wk[t]; bvl[t] = bv[t]; }
    __syncthreads();

    const int tok = t >> 3, oc = t & 7;
    const int e0 = oc * 8;
    float acc[8];
    #pragma unroll
    for (int ee = 0; ee < 8; ++ee) acc[ee] = bvl[e0 + ee];

    for (int d = 0; d < DK; d += 4) {
        float4 x4 = *(const float4*)&x_lds[tok * 68 + d];
        const float xs[4] = {x4.x, x4.y, x4.z, x4.w};
        #pragma unroll
        for (int dd = 0; dd < 4; ++dd) {
            float xv = xs[dd];
            const float4* wrow = (const float4*)&wvt[(d + dd) * 68 + e0];
            float4 wa = wrow[0], wb = wrow[1];
            acc[0] += xv * wa.x; acc[1] += xv * wa.y;
            acc[2] += xv * wa.z; acc[3] += xv * wa.w;
            acc[4] += xv * wb.x; acc[5] += xv * wb.y;
            acc[6] += xv * wb.z; acc[7] += xv * wb.w;
        }
    }
    #pragma unroll
    for (int k = 0; k < 8; ++k) {
        _Float16 hv = (_Float16)acc[k];
        vt_lds[(e0 + k) * 72 + tok] = *(unsigned short*)&hv;
    }

    if (t < 128) {
        const int tk = t & 63;
        const int sel = (t >= 64);
        float a = 0.f;
        for (int d = 0; d < DK; ++d)
            a += x_lds[tk * 68 + d] * wqk[d * 2 + sel];
        (sel ? Ks : Qs)[tok0 + tk] = a * QK_SCALE;
    }
    __syncthreads();

    // fragment-major store
    const int bb = tok0 >> 12, n0 = tok0 & 4095;
    {
        const int c = t >> 6, d = t & 63;
        uint4 v = *(const uint4*)((const char*)vt_lds + d * 144 + c * 16);
        const int jc   = (n0 >> 5) + (c >> 2);
        const int lane = (c & 3) * 16 + (d & 15);
        const int ct   = d >> 4;
        unsigned short* dst = Vt + ((((size_t)bb * 128 + jc) * 4 + ct) * 64 + lane) * 8;
        *(uint4*)dst = v;
    }
}

// ---------------------------------------------------------------------------
// Kernel B: MFMA attention + residual + layernorm.
// 256 blocks x 1024 threads (16 waves). XCD swizzle: batch b owns XCD pair
// {2b,2b+1} -> Vt slice (512 KB) is L2-resident.
// NO V staging, NO K-loop barriers: B-fragments load DIRECTLY from global
// (fragment-major => one coalesced 1 KB transaction per fragment). Waves
// free-run between the k_lds barrier and the combine barrier.
// Wave (rgrp = w>>3: 32 rows, js = w&7: 512-j share, 16 k-steps of 32 j).
// Scores: f32 exp2 -> cvt_pkrtz -> packed-f16 poly. mfma_f32_16x16x32_f16.
// Denominator via ones-MFMA. LDS: k 16 KB | red 8x64x68 (139 KB) | dred 2 KB.
// ---------------------------------------------------------------------------
extern __shared__ float smem[];

__global__ __launch_bounds__(1024, 4) void attn_kernel(
    const float* __restrict__ x,
    const float* __restrict__ Qsg, const float* __restrict__ Ksg,
    const unsigned short* __restrict__ Vt,
    const float* __restrict__ gamma, const float* __restrict__ beta,
    float* __restrict__ out, int nrep)
{
    float* k_lds = smem;                          // 4096 floats
    float* red   = smem + 4096;                   // 8 slots x 64 x 68
    float* dred  = smem + 4096 + 8 * 64 * 68;     // 8 x 64

    const int t    = threadIdx.x;
    const int B    = blockIdx.x;
    const int b    = (B & 7) >> 1;                         // batch <- XCD pair
    const int i0   = (((B >> 3) << 1) | (B & 1)) << 6;     // i-tile
    const int w    = t >> 6;
    const int lane = t & 63;
    const int rit  = lane & 15;
    const int q    = lane >> 4;
    const int rgrp = w >> 3;          // 0..1: 32-row group
    const int js   = w & 7;           // 0..7: 512-j share (16 k-steps)

    ((float4*)k_lds)[t] = ((const float4*)(Ksg + (size_t)b * 4096))[t];

    const float Qs0 = Qsg[b * 4096 + i0 + rgrp * 32 + rit];
    const float Qs1 = Qsg[b * 4096 + i0 + rgrp * 32 + 16 + rit];

    const _Float16 onef = (_Float16)1.0f;
    const half8 vones = {onef, onef, onef, onef, onef, onef, onef, onef};
    const half2v c2 = {(_Float16)3.2552083e-4f, (_Float16)3.2552083e-4f};
    const half2v c1 = {(_Float16)7.8125e-3f, (_Float16)7.8125e-3f};
    const half2v c0 = {(_Float16)0.125f, (_Float16)0.125f};
    const half2v h1 = {onef, onef};

    // wave's j share: jc_global = js*16 + c, c = 0..15
    const unsigned short* vb = Vt + (size_t)b * 262144 + (size_t)(js * 16) * 2048 + lane * 8;
    const float* kp = k_lds + js * 512 + q * 8;

    __syncthreads();   // k_lds ready

    for (int rep = 0; rep < nrep; ++rep) {

    f32x4 acc[2][4] = {};
    f32x4 accd[2] = {};

    for (int c = 0; c < 16; ++c) {
        // ---- B fragments: 4 coalesced 1 KB global loads (L2-resident)
        const unsigned short* vf = vb + c * 2048;
        uint4 bu0 = *(const uint4*)(vf);
        uint4 bu1 = *(const uint4*)(vf + 512);
        uint4 bu2 = *(const uint4*)(vf + 1024);
        uint4 bu3 = *(const uint4*)(vf + 1536);

        const float* kn = kp + c * 32;             // LDS broadcast reads
        float4 ka = *(const float4*)(kn);
        float4 kb = *(const float4*)(kn + 4);
        float kv[8] = {ka.x, ka.y, ka.z, ka.w, kb.x, kb.y, kb.z, kb.w};

        // ---- scores: f32 exp2 -> packed f16 poly (A-frag built packed)
        half2v w0p[4], w1p[4];
        #pragma unroll
        for (int jp = 0; jp < 4; ++jp) {
            float d0a = Qs0 - kv[2 * jp],     d0b = Qs0 - kv[2 * jp + 1];
            float g0a = fast_exp2(-d0a * d0a), g0b = fast_exp2(-d0b * d0b);
            half2v g0 = pack_f16(g0a, g0b);
            w0p[jp] = g0 * (g0 * (g0 * c2 + c1) + c0) + h1;  // exp(g/8)

            float d1a = Qs1 - kv[2 * jp],     d1b = Qs1 - kv[2 * jp + 1];
            float g1a = fast_exp2(-d1a * d1a), g1b = fast_exp2(-d1b * d1b);
            half2v g1 = pack_f16(g1a, g1b);
            w1p[jp] = g1 * (g1 * (g1 * c2 + c1) + c0) + h1;
        }
        union { half2v p[4]; half8 h; } ua0, ua1;
        #pragma unroll
        for (int jp = 0; jp < 4; ++jp) { ua0.p[jp] = w0p[jp]; ua1.p[jp] = w1p[jp]; }
        half8 a0 = ua0.h, a1 = ua1.h;

        half8 b0 = u4_to_h8(bu0), b1 = u4_to_h8(bu1);
        half8 b2 = u4_to_h8(bu2), b3 = u4_to_h8(bu3);
        acc[0][0] = __builtin_amdgcn_mfma_f32_16x16x32_f16(a0, b0, acc[0][0], 0, 0, 0);
        acc[0][1] = __builtin_amdgcn_mfma_f32_16x16x32_f16(a0, b1, acc[0][1], 0, 0, 0);
        acc[0][2] = __builtin_amdgcn_mfma_f32_16x16x32_f16(a0, b2, acc[0][2], 0, 0, 0);
        acc[0][3] = __builtin_amdgcn_mfma_f32_16x16x32_f16(a0, b3, acc[0][3], 0, 0, 0);
        acc[1][0] = __builtin_amdgcn_mfma_f32_16x16x32_f16(a1, b0, acc[1][0], 0, 0, 0);
        acc[1][1] = __builtin_amdgcn_mfma_f32_16x16x32_f16(a1, b1, acc[1][1], 0, 0, 0);
        acc[1][2] = __builtin_amdgcn_mfma_f32_16x16x32_f16(a1, b2, acc[1][2], 0, 0, 0);
        acc[1][3] = __builtin_amdgcn_mfma_f32_16x16x32_f16(a1, b3, acc[1][3], 0, 0, 0);
        accd[0]   = __builtin_amdgcn_mfma_f32_16x16x32_f16(a0, vones, accd[0], 0, 0, 0);
        accd[1]   = __builtin_amdgcn_mfma_f32_16x16x32_f16(a1, vones, accd[1], 0, 0, 0);
    }

    // ---- write partials into red
    {
        float* rbase = red + (size_t)js * (64 * 68);
        #pragma unroll
        for (int rt = 0; rt < 2; ++rt)
            #pragma unroll
            for (int ct = 0; ct < 4; ++ct)
                #pragma unroll
                for (int rg = 0; rg < 4; ++rg)
                    rbase[(rgrp * 32 + rt * 16 + q * 4 + rg) * 68 + ct * 16 + rit]
                        = acc[rt][ct][rg];
        if (rit == 0) {
            #pragma unroll
            for (int rt = 0; rt < 2; ++rt)
                #pragma unroll
                for (int rg = 0; rg < 4; ++rg)
                    dred[js * 64 + rgrp * 32 + rt * 16 + q * 4 + rg] = accd[rt][rg];
        }
    }
    __syncthreads();

    // ---- coalesced epilogue: thread = (row, 4 consecutive cols)
    {
        const int row = t >> 4, cg = t & 15, c0i = cg * 4;
        float dsum = 0.f;
        #pragma unroll
        for (int sl = 0; sl < 8; ++sl) dsum += dred[sl * 64 + row];
        const float inv = 1.0f / dsum;
        const size_t rowg = (size_t)(b * 4096 + i0 + row);

        float4 num = make_float4(0.f, 0.f, 0.f, 0.f);
        #pragma unroll
        for (int sl = 0; sl < 8; ++sl) {
            float4 r4 = *(const float4*)&red[(size_t)sl * (64 * 68) + row * 68 + c0i];
            num.x += r4.x; num.y += r4.y; num.z += r4.z; num.w += r4.w;
        }
        const float4 x4 = *(const float4*)(x + rowg * 64 + c0i);
        float4 h;
        h.x = num.x * inv + x4.x;
        h.y = num.y * inv + x4.y;
        h.z = num.z * inv + x4.z;
        h.w = num.w * inv + x4.w;

        float sm = h.x + h.y + h.z + h.w;
        float ss = h.x * h.x + h.y * h.y + h.z * h.z + h.w * h.w;
        #pragma unroll
        for (int m = 1; m < 16; m <<= 1) { sm += __shfl_xor(sm, m); ss += __shfl_xor(ss, m); }
        const float mu   = sm * 0.015625f;
        const float var  = ss * 0.015625f - mu * mu;
        const float rstd = rsqrtf(var + 1e-5f);

        const float4 g4 = *(const float4*)(gamma + c0i);
        const float4 b4 = *(const float4*)(beta + c0i);
        float4 o;
        o.x = (h.x - mu) * rstd * g4.x + b4.x;
        o.y = (h.y - mu) * rstd * g4.y + b4.y;
        o.z = (h.z - mu) * rstd * g4.z + b4.z;
        o.w = (h.w - mu) * rstd * g4.w + b4.w;
        *(float4*)(out + rowg * 64 + c0i) = o;
    }
    __syncthreads();   // rep isolation (nrep>1 is measurement-only)
    }
}

// ---------------------------------------------------------------------------
extern "C" void kernel_launch(void* const* d_in, const int* in_sizes, int n_in,
                              void* d_out, int out_size, void* d_ws, size_t ws_size,
                              hipStream_t stream)
{
    const float* x     = (const float*)d_in[0];
    const float* Wv    = (const float*)d_in[1];
    const float* bv    = (const float*)d_in[2];
    const float* wq    = (const float*)d_in[3];
    const float* wk    = (const float*)d_in[4];
    const float* gamma = (const float*)d_in[5];
    const float* beta  = (const float*)d_in[6];
    float* out = (float*)d_out;

    float* Qs = (float*)d_ws;
    float* Ks = Qs + NTOK;
    unsigned short* Vt = (unsigned short*)(Ks + NTOK);

    // dynamic LDS: k 16384 + red 139264 + dred 2048 = 157696 B
    const int attn_lds = 4096 * 4 + 8 * 64 * 68 * 4 + 8 * 64 * 4;
    (void)hipFuncSetAttribute((const void*)attn_kernel,
                              hipFuncAttributeMaxDynamicSharedMemorySize, attn_lds);

    qkv_kernel<<<dim3(NTOK / 64), dim3(512), 0, stream>>>(x, Wv, bv, wq, wk, Qs, Ks, Vt);
    attn_kernel<<<dim3(NB * (NSEQ / 64)), dim3(1024), attn_lds, stream>>>(
        x, Qs, Ks, Vt, gamma, beta, out, 1);
}

// Round 16
// 89.793 us; speedup vs baseline: 1.6588x; 1.0172x over previous
//
#include <hip/hip_runtime.h>

#define NB   4
#define NSEQ 4096
#define DK   64
#define NTOK (NB * NSEQ)

#define QK_SCALE 1.2011224087864498f   // sqrt(log2(e))

typedef __attribute__((ext_vector_type(8))) _Float16 half8;
typedef __attribute__((ext_vector_type(2))) _Float16 half2v;
typedef __attribute__((ext_vector_type(2))) __fp16 fp16x2;
typedef __attribute__((ext_vector_type(4))) float f32x4;

__device__ __forceinline__ float fast_exp2(float x) {
#if __has_builtin(__builtin_amdgcn_exp2f)
    return __builtin_amdgcn_exp2f(x);
#else
    return exp2f(x);
#endif
}

__device__ __forceinline__ unsigned pack_f16_u32(float a, float b) {
#if __has_builtin(__builtin_amdgcn_cvt_pkrtz)
    union { fp16x2 f; unsigned u; } c;
    c.f = __builtin_amdgcn_cvt_pkrtz(a, b);
    return c.u;
#else
    union { _Float16 h[2]; unsigned u; } c;
    c.h[0] = (_Float16)a; c.h[1] = (_Float16)b;
    return c.u;
#endif
}

__device__ __forceinline__ half8 u4_to_h8(uint4 u) {
    union { uint4 u; half8 h; } c; c.u = u; return c.h;
}

// ---------------------------------------------------------------------------
// Vt global layout FRAGMENT-MAJOR (f16): Vt_frag[b][jc][ct][lane] x 8 f16,
// lane = q*16 + rit holds V[d = ct*16 + rit][j = jc*32 + q*8 .. +8].
// One (jc,ct) block = 64 lanes x 16 B = 1 KB contiguous -> a direct global
// B-fragment load is a single fully-coalesced 1 KB wave transaction.
// ---------------------------------------------------------------------------

// ---------------------------------------------------------------------------
// Kernel A: Qs/Ks = (x.wq/wk)*QK_SCALE, Vt_frag = f16(x@Wv^T+bv)
// ---------------------------------------------------------------------------
__global__ __launch_bounds__(512) void qkv_kernel(
    const float* __restrict__ x, const float* __restrict__ Wv,
    const float* __restrict__ bv, const float* __restrict__ wq,
    const float* __restrict__ wk,
    float* __restrict__ Qs, float* __restrict__ Ks, unsigned short* __restrict__ Vt)
{
    __shared__ float x_lds[64 * 68];
    __shared__ float wvt[64 * 68];        // wvt[d*68+e] = Wv[e*64+d]
    __shared__ float wqk[128];
    __shared__ float bvl[64];
    __shared__ unsigned short vt_lds[64 * 72];   // [e][tok], f16 bits

    const int t = threadIdx.x;
    const int tok0 = blockIdx.x * 64;

    #pragma unroll
    for (int r = 0; r < 2; ++r) {
        int f = t + 512 * r;
        int row = f >> 4, c4 = f & 15;
        float4 v = ((const float4*)(x + (size_t)(tok0 + row) * DK))[c4];
        *(float4*)&x_lds[row * 68 + c4 * 4] = v;
    }
    #pragma unroll
    for (int r = 0; r < 2; ++r) {
        int f = t + 512 * r;
        int e = f >> 4, c4 = f & 15;
        float4 v = ((const float4*)(Wv + e * DK))[c4];
        wvt[(c4 * 4 + 0) * 68 + e] = v.x;
        wvt[(c4 * 4 + 1) * 68 + e] = v.y;
        wvt[(c4 * 4 + 2) * 68 + e] = v.z;
        wvt[(c4 * 4 + 3) * 68 + e] = v.w;
    }
    if (t < 64) { wqk[t * 2] = wq[t]; wqk[t * 2 + 1] = wk[t]; bvl[t] = bv[t]; }
    __syncthreads();

    const int tok = t >> 3, oc = t & 7;
    const int e0 = oc * 8;
    float acc[8];
    #pragma unroll
    for (int ee = 0; ee < 8; ++ee) acc[ee] = bvl[e0 + ee];

    for (int d = 0; d < DK; d += 4) {
        float4 x4 = *(const float4*)&x_lds[tok * 68 + d];
        const float xs[4] = {x4.x, x4.y, x4.z, x4.w};
        #pragma unroll
        for (int dd = 0; dd < 4; ++dd) {
            float xv = xs[dd];
            const float4* wrow = (const float4*)&wvt[(d + dd) * 68 + e0];
            float4 wa = wrow[0], wb = wrow[1];
            acc[0] += xv * wa.x; acc[1] += xv * wa.y;
            acc[2] += xv * wa.z; acc[3] += xv * wa.w;
            acc[4] += xv * wb.x; acc[5] += xv * wb.y;
            acc[6] += xv * wb.z; acc[7] += xv * wb.w;
        }
    }
    #pragma unroll
    for (int k = 0; k < 8; ++k) {
        _Float16 hv = (_Float16)acc[k];
        vt_lds[(e0 + k) * 72 + tok] = *(unsigned short*)&hv;
    }

    if (t < 128) {
        const int tk = t & 63;
        const int sel = (t >= 64);
        float a = 0.f;
        for (int d = 0; d < DK; ++d)
            a += x_lds[tk * 68 + d] * wqk[d * 2 + sel];
        (sel ? Ks : Qs)[tok0 + tk] = a * QK_SCALE;
    }
    __syncthreads();

    // fragment-major store
    const int bb = tok0 >> 12, n0 = tok0 & 4095;
    {
        const int c = t >> 6, d = t & 63;
        uint4 v = *(const uint4*)((const char*)vt_lds + d * 144 + c * 16);
        const int jc   = (n0 >> 5) + (c >> 2);
        const int lane = (c & 3) * 16 + (d & 15);
        const int ct   = d >> 4;
        unsigned short* dst = Vt + ((((size_t)bb * 128 + jc) * 4 + ct) * 64 + lane) * 8;
        *(uint4*)dst = v;
    }
}

// ---------------------------------------------------------------------------
// Kernel B: MFMA attention + residual + layernorm. (r15 structure)
// Scores: f32 exp2 -> 2-term f32 poly (guaranteed single-instr FMAs) ->
// v_cvt_pkrtz pack. No f16 vector arithmetic (avoids scalarization bloat).
// ---------------------------------------------------------------------------
extern __shared__ float smem[];

__global__ __launch_bounds__(1024, 4) void attn_kernel(
    const float* __restrict__ x,
    const float* __restrict__ Qsg, const float* __restrict__ Ksg,
    const unsigned short* __restrict__ Vt,
    const float* __restrict__ gamma, const float* __restrict__ beta,
    float* __restrict__ out, int nrep)
{
    float* k_lds = smem;                          // 4096 floats
    float* red   = smem + 4096;                   // 8 slots x 64 x 68
    float* dred  = smem + 4096 + 8 * 64 * 68;     // 8 x 64

    const int t    = threadIdx.x;
    const int B    = blockIdx.x;
    const int b    = (B & 7) >> 1;                         // batch <- XCD pair
    const int i0   = (((B >> 3) << 1) | (B & 1)) << 6;     // i-tile
    const int w    = t >> 6;
    const int lane = t & 63;
    const int rit  = lane & 15;
    const int q    = lane >> 4;
    const int rgrp = w >> 3;          // 0..1: 32-row group
    const int js   = w & 7;           // 0..7: 512-j share (16 k-steps)

    ((float4*)k_lds)[t] = ((const float4*)(Ksg + (size_t)b * 4096))[t];

    const float Qs0 = Qsg[b * 4096 + i0 + rgrp * 32 + rit];
    const float Qs1 = Qsg[b * 4096 + i0 + rgrp * 32 + 16 + rit];

    const _Float16 onef = (_Float16)1.0f;
    const half8 vones = {onef, onef, onef, onef, onef, onef, onef, onef};

    // wave's j share: jc_global = js*16 + c, c = 0..15
    const unsigned short* vb = Vt + (size_t)b * 262144 + (size_t)(js * 16) * 2048 + lane * 8;
    const float* kp = k_lds + js * 512 + q * 8;

    __syncthreads();   // k_lds ready

    for (int rep = 0; rep < nrep; ++rep) {

    f32x4 acc[2][4] = {};
    f32x4 accd[2] = {};

    for (int c = 0; c < 16; ++c) {
        // ---- B fragments: 4 coalesced 1 KB global loads (L2-resident)
        const unsigned short* vf = vb + c * 2048;
        uint4 bu0 = *(const uint4*)(vf);
        uint4 bu1 = *(const uint4*)(vf + 512);
        uint4 bu2 = *(const uint4*)(vf + 1024);
        uint4 bu3 = *(const uint4*)(vf + 1536);

        const float* kn = kp + c * 32;             // LDS broadcast reads
        float4 ka = *(const float4*)(kn);
        float4 kb = *(const float4*)(kn + 4);
        float kv[8] = {ka.x, ka.y, ka.z, ka.w, kb.x, kb.y, kb.z, kb.w};

        // ---- scores: all-f32 (sub, mul, exp2, 2 fma) then pkrtz pack
        float w0[8], w1[8];
        #pragma unroll
        for (int jj = 0; jj < 8; ++jj) {
            float d0 = Qs0 - kv[jj];
            float g0 = fast_exp2(-d0 * d0);
            float t0 = __builtin_fmaf(g0, 7.8125e-3f, 0.125f);
            w0[jj] = __builtin_fmaf(g0, t0, 1.0f);   // exp(g/8), 2-term, err<3.3e-4
            float d1 = Qs1 - kv[jj];
            float g1 = fast_exp2(-d1 * d1);
            float t1 = __builtin_fmaf(g1, 7.8125e-3f, 0.125f);
            w1[jj] = __builtin_fmaf(g1, t1, 1.0f);
        }
        uint4 au0, au1;
        au0.x = pack_f16_u32(w0[0], w0[1]);
        au0.y = pack_f16_u32(w0[2], w0[3]);
        au0.z = pack_f16_u32(w0[4], w0[5]);
        au0.w = pack_f16_u32(w0[6], w0[7]);
        au1.x = pack_f16_u32(w1[0], w1[1]);
        au1.y = pack_f16_u32(w1[2], w1[3]);
        au1.z = pack_f16_u32(w1[4], w1[5]);
        au1.w = pack_f16_u32(w1[6], w1[7]);
        half8 a0 = u4_to_h8(au0);
        half8 a1 = u4_to_h8(au1);

        half8 b0 = u4_to_h8(bu0), b1 = u4_to_h8(bu1);
        half8 b2 = u4_to_h8(bu2), b3 = u4_to_h8(bu3);
        acc[0][0] = __builtin_amdgcn_mfma_f32_16x16x32_f16(a0, b0, acc[0][0], 0, 0, 0);
        acc[0][1] = __builtin_amdgcn_mfma_f32_16x16x32_f16(a0, b1, acc[0][1], 0, 0, 0);
        acc[0][2] = __builtin_amdgcn_mfma_f32_16x16x32_f16(a0, b2, acc[0][2], 0, 0, 0);
        acc[0][3] = __builtin_amdgcn_mfma_f32_16x16x32_f16(a0, b3, acc[0][3], 0, 0, 0);
        acc[1][0] = __builtin_amdgcn_mfma_f32_16x16x32_f16(a1, b0, acc[1][0], 0, 0, 0);
        acc[1][1] = __builtin_amdgcn_mfma_f32_16x16x32_f16(a1, b1, acc[1][1], 0, 0, 0);
        acc[1][2] = __builtin_amdgcn_mfma_f32_16x16x32_f16(a1, b2, acc[1][2], 0, 0, 0);
        acc[1][3] = __builtin_amdgcn_mfma_f32_16x16x32_f16(a1, b3, acc[1][3], 0, 0, 0);
        accd[0]   = __builtin_amdgcn_mfma_f32_16x16x32_f16(a0, vones, accd[0], 0, 0, 0);
        accd[1]   = __builtin_amdgcn_mfma_f32_16x16x32_f16(a1, vones, accd[1], 0, 0, 0);
    }

    // ---- write partials into red
    {
        float* rbase = red + (size_t)js * (64 * 68);
        #pragma unroll
        for (int rt = 0; rt < 2; ++rt)
            #pragma unroll
            for (int ct = 0; ct < 4; ++ct)
                #pragma unroll
                for (int rg = 0; rg < 4; ++rg)
                    rbase[(rgrp * 32 + rt * 16 + q * 4 + rg) * 68 + ct * 16 + rit]
                        = acc[rt][ct][rg];
        if (rit == 0) {
            #pragma unroll
            for (int rt = 0; rt < 2; ++rt)
                #pragma unroll
                for (int rg = 0; rg < 4; ++rg)
                    dred[js * 64 + rgrp * 32 + rt * 16 + q * 4 + rg] = accd[rt][rg];
        }
    }
    __syncthreads();

    // ---- coalesced epilogue: thread = (row, 4 consecutive cols)
    {
        const int row = t >> 4, cg = t & 15, c0i = cg * 4;
        float dsum = 0.f;
        #pragma unroll
        for (int sl = 0; sl < 8; ++sl) dsum += dred[sl * 64 + row];
        const float inv = 1.0f / dsum;
        const size_t rowg = (size_t)(b * 4096 + i0 + row);

        float4 num = make_float4(0.f, 0.f, 0.f, 0.f);
        #pragma unroll
        for (int sl = 0; sl < 8; ++sl) {
            float4 r4 = *(const float4*)&red[(size_t)sl * (64 * 68) + row * 68 + c0i];
            num.x += r4.x; num.y += r4.y; num.z += r4.z; num.w += r4.w;
        }
        const float4 x4 = *(const float4*)(x + rowg * 64 + c0i);
        float4 h;
        h.x = num.x * inv + x4.x;
        h.y = num.y * inv + x4.y;
        h.z = num.z * inv + x4.z;
        h.w = num.w * inv + x4.w;

        float sm = h.x + h.y + h.z + h.w;
        float ss = h.x * h.x + h.y * h.y + h.z * h.z + h.w * h.w;
        #pragma unroll
        for (int m = 1; m < 16; m <<= 1) { sm += __shfl_xor(sm, m); ss += __shfl_xor(ss, m); }
        const float mu   = sm * 0.015625f;
        const float var  = ss * 0.015625f - mu * mu;
        const float rstd = rsqrtf(var + 1e-5f);

        const float4 g4 = *(const float4*)(gamma + c0i);
        const float4 b4 = *(const float4*)(beta + c0i);
        float4 o;
        o.x = (h.x - mu) * rstd * g4.x + b4.x;
        o.y = (h.y - mu) * rstd * g4.y + b4.y;
        o.z = (h.z - mu) * rstd * g4.z + b4.z;
        o.w = (h.w - mu) * rstd * g4.w + b4.w;
        *(float4*)(out + rowg * 64 + c0i) = o;
    }
    __syncthreads();   // rep isolation (nrep>1 is measurement-only)
    }
}

// ---------------------------------------------------------------------------
extern "C" void kernel_launch(void* const* d_in, const int* in_sizes, int n_in,
                              void* d_out, int out_size, void* d_ws, size_t ws_size,
                              hipStream_t stream)
{
    const float* x     = (const float*)d_in[0];
    const float* Wv    = (const float*)d_in[1];
    const float* bv    = (const float*)d_in[2];
    const float* wq    = (const float*)d_in[3];
    const float* wk    = (const float*)d_in[4];
    const float* gamma = (const float*)d_in[5];
    const float* beta  = (const float*)d_in[6];
    float* out = (float*)d_out;

    float* Qs = (float*)d_ws;
    float* Ks = Qs + NTOK;
    unsigned short* Vt = (unsigned short*)(Ks + NTOK);

    // dynamic LDS: k 16384 + red 139264 + dred 2048 = 157696 B
    const int attn_lds = 4096 * 4 + 8 * 64 * 68 * 4 + 8 * 64 * 4;
    (void)hipFuncSetAttribute((const void*)attn_kernel,
                              hipFuncAttributeMaxDynamicSharedMemorySize, attn_lds);

    qkv_kernel<<<dim3(NTOK / 64), dim3(512), 0, stream>>>(x, Wv, bv, wq, wk, Qs, Ks, Vt);
    attn_kernel<<<dim3(NB * (NSEQ / 64)), dim3(1024), attn_lds, stream>>>(
        x, Qs, Ks, Vt, gamma, beta, out, 1);
}